// Round 1
// baseline (639.585 us; speedup 1.0000x reference)
//
#include <hip/hip_runtime.h>
#include <hip/hip_bf16.h>

// bf16 MFMA fragment types (gfx950: 16x16x32, 8 bf16 inputs / 4 f32 acc per lane)
typedef __attribute__((ext_vector_type(8))) short bf16x8;
typedef __attribute__((ext_vector_type(4))) float f32x4;

#define DD 128

static __device__ __forceinline__ unsigned short f2bf(float f) {
    unsigned int u = __builtin_bit_cast(unsigned int, f);
    u += 0x7fffu + ((u >> 16) & 1u);   // RNE
    return (unsigned short)(u >> 16);
}
static __device__ __forceinline__ float bf2f(unsigned short h) {
    unsigned int u = ((unsigned int)h) << 16;
    return __builtin_bit_cast(float, u);
}

// ---------------- weight conversion: 6 matrices fp32 -> bf16 in ws ----------------
__global__ void k_convert(const float* __restrict__ w0, const float* __restrict__ w1,
                          const float* __restrict__ w2, const float* __restrict__ w3,
                          const float* __restrict__ w4, const float* __restrict__ w5,
                          unsigned short* __restrict__ wbf) {
    int i = blockIdx.x * blockDim.x + threadIdx.x;
    if (i >= 6 * 16384) return;
    int m = i >> 14, k = i & 16383;
    const float* s = (m == 0) ? w0 : (m == 1) ? w1 : (m == 2) ? w2 : (m == 3) ? w3
                     : (m == 4) ? w4 : w5;
    wbf[i] = f2bf(s[k]);
}

// ---------------- node pooling: Vp = lrelu(lrelu(V)@Wp1^T+bp1)@Wp2^T+bp2 ----------
__global__ __launch_bounds__(256, 2) void k_nodes(
    const float* __restrict__ V, const unsigned short* __restrict__ wbf,
    const float* __restrict__ bp1, const float* __restrict__ bp2,
    unsigned short* __restrict__ Vp, int nN, int nTiles)
{
    const int lane = threadIdx.x & 63;
    const int wave = threadIdx.x >> 6;     // 0..3, owns cols [wave*32, wave*32+32)
    const int lr = lane & 15, lg = lane >> 4;

    bf16x8 B1[2][4], B2[2][4];
#pragma unroll
    for (int ct = 0; ct < 2; ++ct)
#pragma unroll
        for (int kk = 0; kk < 4; ++kk) {
            int j = wave * 32 + ct * 16 + lr;
            int k0 = kk * 32 + lg * 8;
            B1[ct][kk] = *(const bf16x8*)(wbf + 0 * 16384 + j * DD + k0);
            B2[ct][kk] = *(const bf16x8*)(wbf + 1 * 16384 + j * DD + k0);
        }
    float b1v[2], b2v[2];
#pragma unroll
    for (int ct = 0; ct < 2; ++ct) {
        int c = wave * 32 + ct * 16 + lr;
        b1v[ct] = bp1[c]; b2v[ct] = bp2[c];
    }
    __shared__ alignas(16) unsigned short xb[32][136];  // +8 pad: conflict-free b128 reads

    for (int t = blockIdx.x; t < nTiles; t += gridDim.x) {
        const int r0 = t * 32;
        bf16x8 A[2][4];
#pragma unroll
        for (int rg = 0; rg < 2; ++rg)
#pragma unroll
            for (int kk = 0; kk < 4; ++kk) {
                int row = r0 + rg * 16 + lr; if (row >= nN) row = nN - 1;
                const float4* p = (const float4*)(V + (size_t)row * DD + kk * 32 + lg * 8);
                float4 f0 = p[0], f1 = p[1];
                float v[8] = {f0.x, f0.y, f0.z, f0.w, f1.x, f1.y, f1.z, f1.w};
                bf16x8 a;
#pragma unroll
                for (int e = 0; e < 8; ++e) {
                    float x = v[e];
                    x = x > 0.f ? x : 0.2f * x;     // lrelu(V) before first GEMM
                    a[e] = (short)f2bf(x);
                }
                A[rg][kk] = a;
            }
        // G1 + bias + lrelu -> LDS
#pragma unroll
        for (int rg = 0; rg < 2; ++rg)
#pragma unroll
            for (int ct = 0; ct < 2; ++ct) {
                f32x4 acc = {0.f, 0.f, 0.f, 0.f};
#pragma unroll
                for (int kk = 0; kk < 4; ++kk)
                    acc = __builtin_amdgcn_mfma_f32_16x16x32_bf16(A[rg][kk], B1[ct][kk], acc, 0, 0, 0);
#pragma unroll
                for (int r = 0; r < 4; ++r) {
                    float x = acc[r] + b1v[ct];
                    x = x > 0.f ? x : 0.2f * x;
                    xb[rg * 16 + lg * 4 + r][wave * 32 + ct * 16 + lr] = f2bf(x);
                }
            }
        __syncthreads();
        // G2 + bias -> Vp (bf16)
        bf16x8 A2[2][4];
#pragma unroll
        for (int rg = 0; rg < 2; ++rg)
#pragma unroll
            for (int kk = 0; kk < 4; ++kk)
                A2[rg][kk] = *(const bf16x8*)&xb[rg * 16 + lr][kk * 32 + lg * 8];
#pragma unroll
        for (int rg = 0; rg < 2; ++rg)
#pragma unroll
            for (int ct = 0; ct < 2; ++ct) {
                f32x4 acc = {0.f, 0.f, 0.f, 0.f};
#pragma unroll
                for (int kk = 0; kk < 4; ++kk)
                    acc = __builtin_amdgcn_mfma_f32_16x16x32_bf16(A2[rg][kk], B2[ct][kk], acc, 0, 0, 0);
#pragma unroll
                for (int r = 0; r < 4; ++r) {
                    int row = r0 + rg * 16 + lg * 4 + r;
                    if (row < nN)
                        Vp[(size_t)row * DD + wave * 32 + ct * 16 + lr] = f2bf(acc[r] + b2v[ct]);
                }
            }
        __syncthreads();   // single-buffer LDS: protect against next tile's writes
    }
}

// ---------------- fused edge pipeline + gather + scatter-sum ----------------------
__global__ __launch_bounds__(256, 2) void k_edges(
    const float* __restrict__ E, const int* __restrict__ src, const int* __restrict__ dst,
    const unsigned short* __restrict__ wbf,
    const float* __restrict__ bA1, const float* __restrict__ bA2,
    const float* __restrict__ bB, const float* __restrict__ bC,
    const unsigned short* __restrict__ Vp, float* __restrict__ out, int nE, int nTiles)
{
    const int lane = threadIdx.x & 63;
    const int wave = threadIdx.x >> 6;
    const int lr = lane & 15, lg = lane >> 4;

    bf16x8 B1[2][4], B2[2][4], B3[2][4], B4[2][4];
#pragma unroll
    for (int ct = 0; ct < 2; ++ct)
#pragma unroll
        for (int kk = 0; kk < 4; ++kk) {
            int j = wave * 32 + ct * 16 + lr;
            int k0 = kk * 32 + lg * 8;
            const unsigned short* p = wbf + 2 * 16384 + j * DD + k0;
            B1[ct][kk] = *(const bf16x8*)(p);            // WA1
            B2[ct][kk] = *(const bf16x8*)(p + 16384);    // WA2
            B3[ct][kk] = *(const bf16x8*)(p + 32768);    // WB
            B4[ct][kk] = *(const bf16x8*)(p + 49152);    // WC
        }
    float b1v[2], b2v[2], b3v[2], b4v[2];
#pragma unroll
    for (int ct = 0; ct < 2; ++ct) {
        int c = wave * 32 + ct * 16 + lr;
        b1v[ct] = bA1[c]; b2v[ct] = bA2[c]; b3v[ct] = bB[c]; b4v[ct] = bC[c];
    }
    __shared__ alignas(16) unsigned short xb[2][32][136];

    for (int t = blockIdx.x; t < nTiles; t += gridDim.x) {
        const int r0 = t * 32;
        bf16x8 A[2][4];
#pragma unroll
        for (int rg = 0; rg < 2; ++rg)
#pragma unroll
            for (int kk = 0; kk < 4; ++kk) {
                int row = r0 + rg * 16 + lr; if (row >= nE) row = nE - 1;
                const float4* p = (const float4*)(E + (size_t)row * DD + kk * 32 + lg * 8);
                float4 f0 = p[0], f1 = p[1];
                bf16x8 a;
                a[0] = (short)f2bf(f0.x); a[1] = (short)f2bf(f0.y);
                a[2] = (short)f2bf(f0.z); a[3] = (short)f2bf(f0.w);
                a[4] = (short)f2bf(f1.x); a[5] = (short)f2bf(f1.y);
                a[6] = (short)f2bf(f1.z); a[7] = (short)f2bf(f1.w);
                A[rg][kk] = a;
            }
        int si[8], di[8]; bool val[8];
#pragma unroll
        for (int rg = 0; rg < 2; ++rg)
#pragma unroll
            for (int r = 0; r < 4; ++r) {
                int row = r0 + rg * 16 + lg * 4 + r;
                val[rg * 4 + r] = (row < nE);
                if (row >= nE) row = nE - 1;
                si[rg * 4 + r] = src[row];
                di[rg * 4 + r] = dst[row];
            }
        // G1: x1 = relu(E@WA1^T + bA1) -> xb[0]
#pragma unroll
        for (int rg = 0; rg < 2; ++rg)
#pragma unroll
            for (int ct = 0; ct < 2; ++ct) {
                f32x4 acc = {0.f, 0.f, 0.f, 0.f};
#pragma unroll
                for (int kk = 0; kk < 4; ++kk)
                    acc = __builtin_amdgcn_mfma_f32_16x16x32_bf16(A[rg][kk], B1[ct][kk], acc, 0, 0, 0);
#pragma unroll
                for (int r = 0; r < 4; ++r) {
                    float x = fmaxf(acc[r] + b1v[ct], 0.f);
                    xb[0][rg * 16 + lg * 4 + r][wave * 32 + ct * 16 + lr] = f2bf(x);
                }
            }
        __syncthreads();
        // G2: x = x1@WA2^T + bA2 -> xb[1]
        bf16x8 A2[2][4];
#pragma unroll
        for (int rg = 0; rg < 2; ++rg)
#pragma unroll
            for (int kk = 0; kk < 4; ++kk)
                A2[rg][kk] = *(const bf16x8*)&xb[0][rg * 16 + lr][kk * 32 + lg * 8];
#pragma unroll
        for (int rg = 0; rg < 2; ++rg)
#pragma unroll
            for (int ct = 0; ct < 2; ++ct) {
                f32x4 acc = {0.f, 0.f, 0.f, 0.f};
#pragma unroll
                for (int kk = 0; kk < 4; ++kk)
                    acc = __builtin_amdgcn_mfma_f32_16x16x32_bf16(A2[rg][kk], B2[ct][kk], acc, 0, 0, 0);
#pragma unroll
                for (int r = 0; r < 4; ++r)
                    xb[1][rg * 16 + lg * 4 + r][wave * 32 + ct * 16 + lr] = f2bf(acc[r] + b2v[ct]);
            }
        __syncthreads();
        // G3/G4: scale = sigmoid(x@WB^T+bB), shift = x@WC^T+bC; msg; scatter
        bf16x8 A3[2][4];
#pragma unroll
        for (int rg = 0; rg < 2; ++rg)
#pragma unroll
            for (int kk = 0; kk < 4; ++kk)
                A3[rg][kk] = *(const bf16x8*)&xb[1][rg * 16 + lr][kk * 32 + lg * 8];
#pragma unroll
        for (int rg = 0; rg < 2; ++rg)
#pragma unroll
            for (int ct = 0; ct < 2; ++ct) {
                f32x4 aB = {0.f, 0.f, 0.f, 0.f}, aC = {0.f, 0.f, 0.f, 0.f};
#pragma unroll
                for (int kk = 0; kk < 4; ++kk) {
                    aB = __builtin_amdgcn_mfma_f32_16x16x32_bf16(A3[rg][kk], B3[ct][kk], aB, 0, 0, 0);
                    aC = __builtin_amdgcn_mfma_f32_16x16x32_bf16(A3[rg][kk], B4[ct][kk], aC, 0, 0, 0);
                }
                const int col = wave * 32 + ct * 16 + lr;
#pragma unroll
                for (int r = 0; r < 4; ++r) {
                    int idx = rg * 4 + r;
                    float sc = 1.f / (1.f + __expf(-(aB[r] + b3v[ct])));
                    float sh = aC[r] + b4v[ct];
                    float v = bf2f(Vp[(size_t)si[idx] * DD + col]);
                    float msg = sc * v + sh;
                    if (val[idx])
                        unsafeAtomicAdd(out + (size_t)di[idx] * DD + col, msg);
                }
            }
        // no end-of-loop barrier needed: xb[0] reads end before barrier2,
        // xb[1] writes of tile t+1 occur after t+1's barrier1.
    }
}

extern "C" void kernel_launch(void* const* d_in, const int* in_sizes, int n_in,
                              void* d_out, int out_size, void* d_ws, size_t ws_size,
                              hipStream_t stream) {
    const float* V   = (const float*)d_in[0];
    const float* E   = (const float*)d_in[1];
    const int*   src = (const int*)d_in[2];
    const int*   dst = (const int*)d_in[3];
    const float* Wp1 = (const float*)d_in[4];  const float* bp1 = (const float*)d_in[5];
    const float* Wp2 = (const float*)d_in[6];  const float* bp2 = (const float*)d_in[7];
    const float* WA1 = (const float*)d_in[8];  const float* bA1 = (const float*)d_in[9];
    const float* WA2 = (const float*)d_in[10]; const float* bA2 = (const float*)d_in[11];
    const float* WB  = (const float*)d_in[12]; const float* bB  = (const float*)d_in[13];
    const float* WC  = (const float*)d_in[14]; const float* bC  = (const float*)d_in[15];
    float* out = (float*)d_out;

    const int nN = in_sizes[0] / DD;
    const int nE = in_sizes[1] / DD;
    const int nTilesN = (nN + 31) / 32;
    const int nTilesE = (nE + 31) / 32;

    unsigned short* wbf = (unsigned short*)d_ws;                       // 6*16384 u16
    unsigned short* Vp  = (unsigned short*)((char*)d_ws + 196608);     // nN*128 u16

    hipMemsetAsync(d_out, 0, (size_t)out_size * sizeof(float), stream);
    k_convert<<<(6 * 16384 + 255) / 256, 256, 0, stream>>>(Wp1, Wp2, WA1, WA2, WB, WC, wbf);
    int gN = nTilesN < 1024 ? nTilesN : 1024;
    k_nodes<<<gN, 256, 0, stream>>>(V, wbf, bp1, bp2, Vp, nN, nTilesN);
    int gE = nTilesE < 2048 ? nTilesE : 2048;
    k_edges<<<gE, 256, 0, stream>>>(E, src, dst, wbf, bA1, bA2, bB, bC, Vp, out, nE, nTilesE);
}